// Round 1
// 1055.536 us; speedup vs baseline: 1.1502x; 1.1502x over previous
//
#include <hip/hip_runtime.h>

// RNN B=256 T=2048 I=64 H=256 — one workgroup per sample, MFMA matvec recurrence.
// Latency-bound: wall = 2048 serial steps. This version shortens the per-step
// critical path vs the 1214us baseline:
//  1. input projection W_ih.x_t batched per 32-step block as a mini-GEMM with
//     timesteps in the MFMA columns (8 MFMA / wave / 32 steps instead of
//     4 / wave / step) -> per-step chain is W_hh only (16 MFMA, not 20),
//     bias folded into the precomputed xp.
//  2. W_hh accumulation split into kt-parity partials: dependent-MFMA depth
//     8 -> 4; merged with 2 vector adds + scalar selects after the chain.
//  3. step loop hand-unrolled x2 so hbuf ping-pong addresses are loop-invariant.

static constexpr int nB = 256;
static constexpr int nT = 2048;
static constexpr int nI = 64;
static constexpr int nH = 256;
static constexpr int XBLK = 32;     // timesteps of x staged/projected per block
static constexpr int XSTR = 72;     // padded halfword stride of an xbuf row (16B-aligned rows, breaks bank alignment)
static constexpr int THREADS = 512; // 8 waves; wave w owns output rows [32w,32w+32)

typedef _Float16 f16x8 __attribute__((ext_vector_type(8)));
typedef _Float16 f16x4 __attribute__((ext_vector_type(4)));
typedef float f32x4 __attribute__((ext_vector_type(4)));

__device__ __forceinline__ float fast_tanh(float x) {
  float a = fabsf(x);
  float e = __expf(-2.0f * a);           // in (0,1], never overflows
  float r = (1.0f - e) / (1.0f + e);
  return copysignf(r, x);
}

__global__ __launch_bounds__(THREADS, 2)
void rnn_mfma(const float* __restrict__ x, const int* __restrict__ lengths,
              const float* __restrict__ Wih, const float* __restrict__ Whh,
              const float* __restrict__ bih, const float* __restrict__ bhh,
              const float* __restrict__ Wfc, const float* __restrict__ bfc,
              float* __restrict__ out)
{
  __shared__ __align__(16) _Float16 hbuf[2][nH];            // 1 KB
  __shared__ __align__(16) _Float16 xbuf[2][XBLK * XSTR];   // 9 KB
  __shared__ float xp[nH][XBLK + 1];                        // 33.8 KB; +1 pad: read banks (row+s)%32
  __shared__ float red[THREADS / 64];

  const int b   = blockIdx.x;
  const int tid = threadIdx.x;
  const int w   = tid >> 6;       // wave 0..7
  const int l   = tid & 63;
  const int q   = l >> 4;         // quad 0..3
  const int n   = l & 15;         // MFMA column lane
  const int len = lengths[b];     // in [1, nT]
  const float* xb = x + (size_t)b * nT * nI;

  // ---- preamble: pack this wave's W rows into A-fragments (f16)
  // A layout (16x16x32): lane holds A[m = lane&15][k = 8*(lane>>4) + j], j=0..7
  f16x8 Ah[2][8];   // over W_hh, rows 32w+16mt+n, k 32kt+8q+j
  f16x8 Ax[2][2];   // over W_ih (I=64 -> 2 k-tiles), used only in the xp mini-GEMM
#pragma unroll
  for (int mt = 0; mt < 2; ++mt) {
    const int row = 32 * w + 16 * mt + n;
#pragma unroll
    for (int kt = 0; kt < 8; ++kt) {
      const float* src = Whh + row * nH + 32 * kt + 8 * q;
      f16x8 a;
#pragma unroll
      for (int j = 0; j < 8; ++j) a[j] = (_Float16)src[j];
      Ah[mt][kt] = a;
    }
#pragma unroll
    for (int kt = 0; kt < 2; ++kt) {
      const float* src = Wih + row * nI + 32 * kt + 8 * q;
      f16x8 a;
#pragma unroll
      for (int j = 0; j < 8; ++j) a[j] = (_Float16)src[j];
      Ax[mt][kt] = a;
    }
  }
  // bias in C layout: reg r <-> row 32w + 16mt + 4q + r (folded into xp at GEMM init)
  f32x4 biasC[2];
#pragma unroll
  for (int r = 0; r < 4; ++r) {
    const int r0 = 32 * w + 4 * q + r;
    biasC[0][r] = bih[r0] + bhh[r0];
    biasC[1][r] = bih[r0 + 16] + bhh[r0 + 16];
  }
  // column-split ownership: lane finishes exactly one output row per step
  const int mt_sel  = (n >> 2) & 1;
  const int reg_sel = n & 3;
  const int row_own = 32 * w + 16 * mt_sel + 4 * q + reg_sel;

  // x staging geometry: thread writes 4 halfs at (row xrow, col xcol) of the block
  const int xrow = (tid * 4) >> 6;   // 0..31
  const int xcol = (tid * 4) & 63;
  const int xoff = xrow * XSTR + xcol;

  // ---- h0 = 0; stage x block 0
  if (tid < nH) hbuf[0][tid] = (_Float16)0.f;
  {
    float4 v = *(const float4*)(xb + tid * 4);
    f16x4 pv = { (_Float16)v.x, (_Float16)v.y, (_Float16)v.z, (_Float16)v.w };
    *(f16x4*)(xbuf[0] + xoff) = pv;
  }
  __syncthreads();

  int t = 0;
  for (int blk = 0; t < len; ++blk) {
    float4 pre;
    const bool havepre = ((blk + 1) * XBLK < len);
    if (havepre)
      pre = *(const float4*)(xb + (size_t)(blk + 1) * XBLK * nI + tid * 4);

    // ---- xp mini-GEMM: xp[row][s] = bias + W_ih . x_{blk*32+s}, timesteps as columns.
    // B[k][col] = x[s = 16ct + col][k]; C cols are timesteps -> 8 MFMAs cover 32 steps.
    {
      const _Float16* xB = xbuf[blk & 1];
      f32x4 g00 = biasC[0], g01 = biasC[0], g10 = biasC[1], g11 = biasC[1];
#pragma unroll
      for (int kt = 0; kt < 2; ++kt) {
        f16x8 B0 = *(const f16x8*)(xB + n * XSTR + 32 * kt + 8 * q);         // ct=0
        f16x8 B1 = *(const f16x8*)(xB + (16 + n) * XSTR + 32 * kt + 8 * q);  // ct=1
        g00 = __builtin_amdgcn_mfma_f32_16x16x32_f16(Ax[0][kt], B0, g00, 0, 0, 0);
        g10 = __builtin_amdgcn_mfma_f32_16x16x32_f16(Ax[1][kt], B0, g10, 0, 0, 0);
        g01 = __builtin_amdgcn_mfma_f32_16x16x32_f16(Ax[0][kt], B1, g01, 0, 0, 0);
        g11 = __builtin_amdgcn_mfma_f32_16x16x32_f16(Ax[1][kt], B1, g11, 0, 0, 0);
      }
      // C layout: lane (q,n) holds C[row = 4q+r (in tile)][col = n]
#pragma unroll
      for (int r = 0; r < 4; ++r) {
        const int r0 = 32 * w + 4 * q + r;
        xp[r0][n]           = g00[r];
        xp[r0 + 16][n]      = g10[r];
        xp[r0][16 + n]      = g01[r];
        xp[r0 + 16][16 + n] = g11[r];
      }
    }
    __syncthreads();   // xp visible (prev block's xp reads completed before its last barrier)

    const int nsteps = min(XBLK, len - blk * XBLK);

    auto step = [&](int s, const _Float16* hsrc, _Float16* hdst) {
      float xpv = xp[row_own][s];   // conflict-free; latency hides under h reads/MFMA
      f32x4 z = {0.f, 0.f, 0.f, 0.f};
      f32x4 p00 = z, p01 = z, p10 = z, p11 = z;  // kt-parity partials: chain depth 4
#pragma unroll
      for (int kt = 0; kt < 8; kt += 2) {
        f16x8 Be = *(const f16x8*)(hsrc + 32 * kt + 8 * q);
        f16x8 Bo = *(const f16x8*)(hsrc + 32 * (kt + 1) + 8 * q);
        p00 = __builtin_amdgcn_mfma_f32_16x16x32_f16(Ah[0][kt],     Be, p00, 0, 0, 0);
        p10 = __builtin_amdgcn_mfma_f32_16x16x32_f16(Ah[1][kt],     Be, p10, 0, 0, 0);
        p01 = __builtin_amdgcn_mfma_f32_16x16x32_f16(Ah[0][kt + 1], Bo, p01, 0, 0, 0);
        p11 = __builtin_amdgcn_mfma_f32_16x16x32_f16(Ah[1][kt + 1], Bo, p11, 0, 0, 0);
      }
      f32x4 s0 = p00 + p01;
      f32x4 s1 = p10 + p11;
      float lo0 = (reg_sel & 1) ? s0[1] : s0[0];
      float hi0 = (reg_sel & 1) ? s0[3] : s0[2];
      float v0  = (reg_sel & 2) ? hi0 : lo0;
      float lo1 = (reg_sel & 1) ? s1[1] : s1[0];
      float hi1 = (reg_sel & 1) ? s1[3] : s1[2];
      float v1  = (reg_sel & 2) ? hi1 : lo1;
      float v   = (mt_sel ? v1 : v0) + xpv;
      float hn  = fast_tanh(v);

      // fold next-x writeback in before this block's final barrier
      if (s == nsteps - 1 && havepre) {
        f16x4 pv = { (_Float16)pre.x, (_Float16)pre.y, (_Float16)pre.z, (_Float16)pre.w };
        *(f16x4*)(xbuf[(blk + 1) & 1] + xoff) = pv;
      }
      if (n < 8) hdst[row_own] = (_Float16)hn;
      __syncthreads();
    };

    // t parity == s parity (blk*XBLK even): unroll x2 with static buffers
    int s = 0;
    for (; s + 2 <= nsteps; s += 2) {
      step(s,     hbuf[0], hbuf[1]);
      step(s + 1, hbuf[1], hbuf[0]);
    }
    if (s < nsteps) step(s, hbuf[0], hbuf[1]);
    t += nsteps;
  }

  // ---- epilogue: out[b] = h_final . W_fc + b_fc
  float v = 0.f;
  if (tid < nH) v = (float)hbuf[len & 1][tid] * Wfc[tid];
#pragma unroll
  for (int off = 32; off; off >>= 1) v += __shfl_down(v, off);
  if (l == 0) red[w] = v;
  __syncthreads();
  if (tid == 0) {
    float acc = bfc[0];
#pragma unroll
    for (int i = 0; i < THREADS / 64; ++i) acc += red[i];
    out[b] = acc;
  }
}

extern "C" void kernel_launch(void* const* d_in, const int* in_sizes, int n_in,
                              void* d_out, int out_size, void* d_ws, size_t ws_size,
                              hipStream_t stream) {
  const float* x   = (const float*)d_in[0];
  const int* lens  = (const int*)d_in[1];
  const float* Wih = (const float*)d_in[2];
  const float* Whh = (const float*)d_in[3];
  const float* bih = (const float*)d_in[4];
  const float* bhh = (const float*)d_in[5];
  const float* Wfc = (const float*)d_in[6];
  const float* bfc = (const float*)d_in[7];
  float* out = (float*)d_out;

  rnn_mfma<<<nB, THREADS, 0, stream>>>(x, lens, Wih, Whh, bih, bhh, Wfc, bfc, out);
}